// Round 3
// baseline (280.054 us; speedup 1.0000x reference)
//
#include <hip/hip_runtime.h>

typedef __attribute__((ext_vector_type(8))) short bf16x8;
typedef __attribute__((ext_vector_type(4))) float f32x4;

#define T_STEPS 49
#define BM 16
#define OUTSTRIDE (4096*64)

__device__ __forceinline__ short f2bf(float x) {
  unsigned u = __builtin_bit_cast(unsigned, x);
  u += 0x7FFFu + ((u >> 16) & 1u);   // round-to-nearest-even
  return (short)(u >> 16);
}
__device__ __forceinline__ float bf2f(short b) {
  return __builtin_bit_cast(float, ((unsigned)(unsigned short)b) << 16);
}
__device__ __forceinline__ float fast_tanh(float x) {
  float e = __builtin_amdgcn_exp2f(x * 2.885390081777927f);
  return 1.f - 2.f * __builtin_amdgcn_rcpf(e + 1.f);
}

// One WG = 16 batch rows, 512 threads = 8 waves. Wave w owns H cols [32w,32w+32)
// in layer 1 and K cols [16w,16w+16) in layer 2. Weights are register-resident.
// LDS: power-of-2 row strides (Y:256B, H:512B); swizzle rule applied to the FULL
// byte address:  addr = (row*stride + col*2) ^ (((row>>2)&3)<<5).
// (R2 bug: H-store XORed the row base before adding col -> carries crossed rows.)
__global__ __launch_bounds__(512)
void node_rk4_kernel(const float* __restrict__ x0, const float* __restrict__ tarr,
                     const float* __restrict__ W1, const float* __restrict__ b1,
                     const float* __restrict__ W2, const float* __restrict__ b2,
                     float* __restrict__ out)
{
  __shared__ __align__(64) short Yhi[16*128];
  __shared__ __align__(64) short Ylo[16*128];
  __shared__ __align__(64) short Hbf[16*256];

  const int tid  = threadIdx.x;
  const int w    = tid >> 6;        // wave 0..7
  const int lane = tid & 63;
  const int m    = lane & 15;       // A-row / B-col / D-col index
  const int g    = lane >> 4;       // 0..3
  const int row0 = (int)blockIdx.x * BM;
  const int col  = 16*w + m;        // this lane's layer-2 output column

  char* Yhc = (char*)Yhi;
  char* Ylc = (char*)Ylo;
  char* Hc  = (char*)Hbf;

  const int rxor = ((m >> 2) & 3) << 5;   // A-reads: row = m
  const int wxor = g << 5;                // state/H writes: row = 4g+i -> (row>>2)&3 = g

  // ---- weight fragments in registers (one-time) ----
  // intra-chunk K mapping: k = kk*32 + 8*g + j  (same for A and B -> safe)
  bf16x8 wB1[2][4], wB2[8];
#pragma unroll
  for (int tt = 0; tt < 2; ++tt)
#pragma unroll
    for (int kk = 0; kk < 4; ++kk) {
      bf16x8 v;
#pragma unroll
      for (int j = 0; j < 8; ++j)
        v[j] = f2bf(W1[(kk*32 + 8*g + j)*256 + (32*w + 16*tt + m)]);
      wB1[tt][kk] = v;
    }
#pragma unroll
  for (int kk = 0; kk < 8; ++kk) {
    bf16x8 v;
#pragma unroll
    for (int j = 0; j < 8; ++j)
      v[j] = f2bf(W2[(kk*32 + 8*g + j)*128 + col]);
    wB2[kk] = v;
  }
  const float bb1a = b1[32*w + m];
  const float bb1b = b1[32*w + 16 + m];
  const float bb2  = b2[col];

  // ---- per-lane fp32 state: rows 4g+i, column `col` ----
  float y[4], k1[4], k2[4], k3[4], yn[4];
#pragma unroll
  for (int i = 0; i < 4; ++i) {
    float v = (col < 64) ? x0[(row0 + 4*g + i)*64 + col] : 0.f;
    y[i] = v; yn[i] = v;
  }
  if (col < 64) {
#pragma unroll
    for (int i = 0; i < 4; ++i)
      out[(row0 + 4*g + i)*64 + col] = y[i];
  }

  for (int step = 0; step < T_STEPS; ++step) {
    const float dt = tarr[step+1] - tarr[step];
    const float third = dt * (1.f/3.f);

#pragma unroll
    for (int stage = 0; stage < 4; ++stage) {
      // stage input -> LDS (hi/lo bf16 split), swizzled scalar writes
#pragma unroll
      for (int i = 0; i < 4; ++i) {
        short hi = f2bf(yn[i]);
        float r  = yn[i] - bf2f(hi);
        int off = (((4*g + i) << 8) + (col << 1)) ^ wxor;
        *(short*)(Yhc + off) = hi;
        *(short*)(Ylc + off) = f2bf(r);
      }
      __syncthreads();

      // layer 1: H = tanh(Y @ W1 + b1)
      f32x4 acc0 = { bb1a, bb1a, bb1a, bb1a };
      f32x4 acc1 = { bb1b, bb1b, bb1b, bb1b };
#pragma unroll
      for (int kk = 0; kk < 4; ++kk) {
        int roff = ((m << 8) + (kk << 6) + (g << 4)) ^ rxor;
        bf16x8 ah = *(const bf16x8*)(Yhc + roff);
        bf16x8 al = *(const bf16x8*)(Ylc + roff);
        acc0 = __builtin_amdgcn_mfma_f32_16x16x32_bf16(ah, wB1[0][kk], acc0, 0,0,0);
        acc1 = __builtin_amdgcn_mfma_f32_16x16x32_bf16(ah, wB1[1][kk], acc1, 0,0,0);
        acc0 = __builtin_amdgcn_mfma_f32_16x16x32_bf16(al, wB1[0][kk], acc0, 0,0,0);
        acc1 = __builtin_amdgcn_mfma_f32_16x16x32_bf16(al, wB1[1][kk], acc1, 0,0,0);
      }
#pragma unroll
      for (int i = 0; i < 4; ++i) {
        int offa = ((((4*g + i) << 9) + ((32*w + m) << 1))      ) ^ wxor;
        int offb = ((((4*g + i) << 9) + ((32*w + 16 + m) << 1)) ) ^ wxor;
        *(short*)(Hc + offa) = f2bf(fast_tanh(acc0[i]));
        *(short*)(Hc + offb) = f2bf(fast_tanh(acc1[i]));
      }
      __syncthreads();

      // layer 2: K = H @ W2 + b2
      f32x4 accA = { bb2, bb2, bb2, bb2 };
      f32x4 accB = { 0.f, 0.f, 0.f, 0.f };
#pragma unroll
      for (int kk = 0; kk < 4; ++kk) {
        bf16x8 aA = *(const bf16x8*)(Hc + (((m << 9) + (kk << 6) + (g << 4)) ^ rxor));
        bf16x8 aB = *(const bf16x8*)(Hc + (((m << 9) + ((kk+4) << 6) + (g << 4)) ^ rxor));
        accA = __builtin_amdgcn_mfma_f32_16x16x32_bf16(aA, wB2[kk],   accA, 0,0,0);
        accB = __builtin_amdgcn_mfma_f32_16x16x32_bf16(aB, wB2[kk+4], accB, 0,0,0);
      }

      // RK4 (3/8 rule) bookkeeping
      if (stage == 0) {
#pragma unroll
        for (int i = 0; i < 4; ++i) { k1[i] = accA[i]+accB[i]; yn[i] = y[i] + third*k1[i]; }
      } else if (stage == 1) {
#pragma unroll
        for (int i = 0; i < 4; ++i) { k2[i] = accA[i]+accB[i]; yn[i] = y[i] + dt*(k2[i] - k1[i]*(1.f/3.f)); }
      } else if (stage == 2) {
#pragma unroll
        for (int i = 0; i < 4; ++i) { k3[i] = accA[i]+accB[i]; yn[i] = y[i] + dt*(k1[i] - k2[i] + k3[i]); }
      } else {
#pragma unroll
        for (int i = 0; i < 4; ++i) {
          float k4 = accA[i]+accB[i];
          y[i] += dt*0.125f*(k1[i] + 3.f*(k2[i]+k3[i]) + k4);
          yn[i] = y[i];
        }
        if (col < 64) {
#pragma unroll
          for (int i = 0; i < 4; ++i)
            out[(step+1)*OUTSTRIDE + (row0 + 4*g + i)*64 + col] = y[i];
        }
      }
    }
  }
}

extern "C" void kernel_launch(void* const* d_in, const int* in_sizes, int n_in,
                              void* d_out, int out_size, void* d_ws, size_t ws_size,
                              hipStream_t stream) {
  const float* x0 = (const float*)d_in[0];
  const float* t  = (const float*)d_in[1];
  const float* W1 = (const float*)d_in[2];
  const float* b1 = (const float*)d_in[3];
  const float* W2 = (const float*)d_in[4];
  const float* b2 = (const float*)d_in[5];
  float* out = (float*)d_out;
  hipLaunchKernelGGL(node_rk4_kernel, dim3(4096/BM), dim3(512), 0, stream,
                     x0, t, W1, b1, W2, b2, out);
}

// Round 4
// 216.349 us; speedup vs baseline: 1.2945x; 1.2945x over previous
//
#include <hip/hip_runtime.h>

typedef __attribute__((ext_vector_type(8))) short bf16x8;
typedef __attribute__((ext_vector_type(4))) short bf16x4;
typedef __attribute__((ext_vector_type(4))) float f32x4;

#define T_STEPS 49
#define BM 16
#define OUTSTRIDE (4096*64)
#define YSTR 132   // shorts/row: 66 dwords = 2 mod 8 -> write rows 4g+i spread 8g across banks
#define HSTR 260   // shorts/row: 130 dwords = 2 mod 8 -> same

__device__ __forceinline__ short f2bf(float x) {
  unsigned u = __builtin_bit_cast(unsigned, x);
  u += 0x7FFFu + ((u >> 16) & 1u);   // round-to-nearest-even
  return (short)(u >> 16);
}
__device__ __forceinline__ float bf2f(short b) {
  return __builtin_bit_cast(float, ((unsigned)(unsigned short)b) << 16);
}
__device__ __forceinline__ float fast_tanh(float x) {
  float e = __builtin_amdgcn_exp2f(x * 2.885390081777927f);
  return 1.f - 2.f * __builtin_amdgcn_rcpf(e + 1.f);
}
__device__ __forceinline__ bf16x8 ld_frag(const short* p) {
  bf16x4 a = *(const bf16x4*)p;        // rows are 8B-aligned (264B/520B strides)
  bf16x4 b = *(const bf16x4*)(p + 4);
  return __builtin_shufflevector(a, b, 0,1,2,3,4,5,6,7);
}

// One WG = 16 batch rows, 512 threads = 8 waves. Wave w owns H cols [32w,32w+32)
// in layer 1 and K cols [16w,16w+16) in layer 2. Weights register-resident.
// LDS row strides chosen so scalar b16 state/H writes are conflict-free:
// stride_dw ≡ 2 (mod 8) -> rows 4g+i map to bank offset 8g (4 distinct octets).
__global__ __launch_bounds__(512)
void node_rk4_kernel(const float* __restrict__ x0, const float* __restrict__ tarr,
                     const float* __restrict__ W1, const float* __restrict__ b1,
                     const float* __restrict__ W2, const float* __restrict__ b2,
                     float* __restrict__ out)
{
  __shared__ __align__(16) short Yhi[16][YSTR];
  __shared__ __align__(16) short Ylo[16][YSTR];
  __shared__ __align__(16) short Hbf[16][HSTR];

  const int tid  = threadIdx.x;
  const int w    = tid >> 6;        // wave 0..7
  const int lane = tid & 63;
  const int m    = lane & 15;       // A-row / B-col / D-col index
  const int g    = lane >> 4;       // 0..3
  const int row0 = (int)blockIdx.x * BM;
  const int col  = 16*w + m;        // this lane's layer-2 output column

  // ---- weight fragments in registers (one-time) ----
  // intra-chunk K mapping: k = kk*32 + 8*g + j  (same for A and B -> safe)
  bf16x8 wB1[2][4], wB2[8];
#pragma unroll
  for (int tt = 0; tt < 2; ++tt)
#pragma unroll
    for (int kk = 0; kk < 4; ++kk) {
      bf16x8 v;
#pragma unroll
      for (int j = 0; j < 8; ++j)
        v[j] = f2bf(W1[(kk*32 + 8*g + j)*256 + (32*w + 16*tt + m)]);
      wB1[tt][kk] = v;
    }
#pragma unroll
  for (int kk = 0; kk < 8; ++kk) {
    bf16x8 v;
#pragma unroll
    for (int j = 0; j < 8; ++j)
      v[j] = f2bf(W2[(kk*32 + 8*g + j)*128 + col]);
    wB2[kk] = v;
  }
  const float bb1a = b1[32*w + m];
  const float bb1b = b1[32*w + 16 + m];
  const float bb2  = b2[col];

  // ---- per-lane fp32 state: rows 4g+i, column `col` ----
  float y[4], k1[4], k2[4], k3[4], yn[4];
#pragma unroll
  for (int i = 0; i < 4; ++i) {
    float v = (col < 64) ? x0[(row0 + 4*g + i)*64 + col] : 0.f;
    y[i] = v; yn[i] = v;
  }
  if (col < 64) {
#pragma unroll
    for (int i = 0; i < 4; ++i)
      out[(row0 + 4*g + i)*64 + col] = y[i];
  }

  for (int step = 0; step < T_STEPS; ++step) {
    const float dt = tarr[step+1] - tarr[step];
    const float third = dt * (1.f/3.f);

#pragma unroll
    for (int stage = 0; stage < 4; ++stage) {
      // stage input -> LDS (hi/lo bf16 split)
#pragma unroll
      for (int i = 0; i < 4; ++i) {
        short hi = f2bf(yn[i]);
        float r  = yn[i] - bf2f(hi);
        Yhi[4*g + i][col] = hi;
        Ylo[4*g + i][col] = f2bf(r);
      }
      __syncthreads();

      // layer 1: H = tanh(Y @ W1 + b1)
      f32x4 acc0 = { bb1a, bb1a, bb1a, bb1a };
      f32x4 acc1 = { bb1b, bb1b, bb1b, bb1b };
#pragma unroll
      for (int kk = 0; kk < 4; ++kk) {
        bf16x8 ah = ld_frag(&Yhi[m][kk*32 + 8*g]);
        bf16x8 al = ld_frag(&Ylo[m][kk*32 + 8*g]);
        acc0 = __builtin_amdgcn_mfma_f32_16x16x32_bf16(ah, wB1[0][kk], acc0, 0,0,0);
        acc1 = __builtin_amdgcn_mfma_f32_16x16x32_bf16(ah, wB1[1][kk], acc1, 0,0,0);
        acc0 = __builtin_amdgcn_mfma_f32_16x16x32_bf16(al, wB1[0][kk], acc0, 0,0,0);
        acc1 = __builtin_amdgcn_mfma_f32_16x16x32_bf16(al, wB1[1][kk], acc1, 0,0,0);
      }
#pragma unroll
      for (int i = 0; i < 4; ++i) {
        Hbf[4*g + i][32*w + m]      = f2bf(fast_tanh(acc0[i]));
        Hbf[4*g + i][32*w + 16 + m] = f2bf(fast_tanh(acc1[i]));
      }
      __syncthreads();

      // layer 2: K = H @ W2 + b2
      f32x4 accA = { bb2, bb2, bb2, bb2 };
      f32x4 accB = { 0.f, 0.f, 0.f, 0.f };
#pragma unroll
      for (int kk = 0; kk < 4; ++kk) {
        bf16x8 aA = ld_frag(&Hbf[m][kk*32 + 8*g]);
        bf16x8 aB = ld_frag(&Hbf[m][(kk+4)*32 + 8*g]);
        accA = __builtin_amdgcn_mfma_f32_16x16x32_bf16(aA, wB2[kk],   accA, 0,0,0);
        accB = __builtin_amdgcn_mfma_f32_16x16x32_bf16(aB, wB2[kk+4], accB, 0,0,0);
      }

      // RK4 (3/8 rule) bookkeeping
      if (stage == 0) {
#pragma unroll
        for (int i = 0; i < 4; ++i) { k1[i] = accA[i]+accB[i]; yn[i] = y[i] + third*k1[i]; }
      } else if (stage == 1) {
#pragma unroll
        for (int i = 0; i < 4; ++i) { k2[i] = accA[i]+accB[i]; yn[i] = y[i] + dt*(k2[i] - k1[i]*(1.f/3.f)); }
      } else if (stage == 2) {
#pragma unroll
        for (int i = 0; i < 4; ++i) { k3[i] = accA[i]+accB[i]; yn[i] = y[i] + dt*(k1[i] - k2[i] + k3[i]); }
      } else {
#pragma unroll
        for (int i = 0; i < 4; ++i) {
          float k4 = accA[i]+accB[i];
          y[i] += dt*0.125f*(k1[i] + 3.f*(k2[i]+k3[i]) + k4);
          yn[i] = y[i];
        }
        if (col < 64) {
#pragma unroll
          for (int i = 0; i < 4; ++i)
            out[(step+1)*OUTSTRIDE + (row0 + 4*g + i)*64 + col] = y[i];
        }
      }
    }
  }
}

extern "C" void kernel_launch(void* const* d_in, const int* in_sizes, int n_in,
                              void* d_out, int out_size, void* d_ws, size_t ws_size,
                              hipStream_t stream) {
  const float* x0 = (const float*)d_in[0];
  const float* t  = (const float*)d_in[1];
  const float* W1 = (const float*)d_in[2];
  const float* b1 = (const float*)d_in[3];
  const float* W2 = (const float*)d_in[4];
  const float* b2 = (const float*)d_in[5];
  float* out = (float*)d_out;
  hipLaunchKernelGGL(node_rk4_kernel, dim3(4096/BM), dim3(512), 0, stream,
                     x0, t, W1, b1, W2, b2, out);
}

// Round 5
// 165.983 us; speedup vs baseline: 1.6872x; 1.3034x over previous
//
#include <hip/hip_runtime.h>

typedef __attribute__((ext_vector_type(8))) _Float16 f16x8;
typedef __attribute__((ext_vector_type(4))) _Float16 f16x4;
typedef __attribute__((ext_vector_type(4))) float f32x4;

#define T_STEPS 49
#define BM 16
#define OUTSTRIDE (4096*64)
#define YSTR 132   // f16/row: 264B = 66 dw == 2 mod 8 -> scalar write rows 4g+i spread 8g across banks
#define HSTR 260   // f16/row: 520B = 130 dw == 2 mod 8 -> same

__device__ __forceinline__ float fast_tanh(float x) {
  float e = __builtin_amdgcn_exp2f(x * 2.885390081777927f);
  return 1.f - 2.f * __builtin_amdgcn_rcpf(e + 1.f);
}
__device__ __forceinline__ f16x8 ld_frag(const _Float16* p) {
  f16x4 a = *(const f16x4*)p;        // rows 8B-aligned
  f16x4 b = *(const f16x4*)(p + 4);
  return __builtin_shufflevector(a, b, 0,1,2,3,4,5,6,7);
}

// One WG = 16 batch rows, 512 threads = 8 waves. Wave w owns H cols [32w,32w+32)
// in layer 1 and K cols [16w,16w+16) in layer 2. Weights register-resident as
// fp16 fragments. Single fp16 pass (2^-11 quantization) replaces R4's bf16
// hi/lo double pass: 128 MFMA/eval/CU instead of 192, and no split arithmetic.
__global__ __launch_bounds__(512)
void node_rk4_kernel(const float* __restrict__ x0, const float* __restrict__ tarr,
                     const float* __restrict__ W1, const float* __restrict__ b1,
                     const float* __restrict__ W2, const float* __restrict__ b2,
                     float* __restrict__ out)
{
  __shared__ __align__(16) _Float16 Yh[16][YSTR];
  __shared__ __align__(16) _Float16 Hh[16][HSTR];

  const int tid  = threadIdx.x;
  const int w    = tid >> 6;        // wave 0..7
  const int lane = tid & 63;
  const int m    = lane & 15;       // A-row / B-col / D-col index
  const int g    = lane >> 4;       // 0..3
  const int row0 = (int)blockIdx.x * BM;
  const int col  = 16*w + m;        // this lane's layer-2 output column

  // ---- weight fragments in registers (one-time) ----
  // intra-chunk K mapping: k = kk*32 + 8*g + j  (same for A and B -> safe)
  f16x8 wB1[2][4], wB2[8];
#pragma unroll
  for (int tt = 0; tt < 2; ++tt)
#pragma unroll
    for (int kk = 0; kk < 4; ++kk) {
      f16x8 v;
#pragma unroll
      for (int j = 0; j < 8; ++j)
        v[j] = (_Float16)W1[(kk*32 + 8*g + j)*256 + (32*w + 16*tt + m)];
      wB1[tt][kk] = v;
    }
#pragma unroll
  for (int kk = 0; kk < 8; ++kk) {
    f16x8 v;
#pragma unroll
    for (int j = 0; j < 8; ++j)
      v[j] = (_Float16)W2[(kk*32 + 8*g + j)*128 + col];
    wB2[kk] = v;
  }
  const float bb1a = b1[32*w + m];
  const float bb1b = b1[32*w + 16 + m];
  const float bb2  = b2[col];

  // ---- per-lane fp32 state: rows 4g+i, column `col` ----
  float y[4], k1[4], k2[4], k3[4], yn[4];
#pragma unroll
  for (int i = 0; i < 4; ++i) {
    float v = (col < 64) ? x0[(row0 + 4*g + i)*64 + col] : 0.f;
    y[i] = v; yn[i] = v;
  }
  if (col < 64) {
#pragma unroll
    for (int i = 0; i < 4; ++i)
      out[(row0 + 4*g + i)*64 + col] = y[i];
  }

  for (int step = 0; step < T_STEPS; ++step) {
    const float dt = tarr[step+1] - tarr[step];
    const float third = dt * (1.f/3.f);

#pragma unroll
    for (int stage = 0; stage < 4; ++stage) {
      // stage input -> LDS (single fp16 write per row)
#pragma unroll
      for (int i = 0; i < 4; ++i)
        Yh[4*g + i][col] = (_Float16)yn[i];
      __syncthreads();

      // layer 1: H = tanh(Y @ W1 + b1)
      f32x4 acc0 = { bb1a, bb1a, bb1a, bb1a };
      f32x4 acc1 = { bb1b, bb1b, bb1b, bb1b };
#pragma unroll
      for (int kk = 0; kk < 4; ++kk) {
        f16x8 a = ld_frag(&Yh[m][kk*32 + 8*g]);
        acc0 = __builtin_amdgcn_mfma_f32_16x16x32_f16(a, wB1[0][kk], acc0, 0,0,0);
        acc1 = __builtin_amdgcn_mfma_f32_16x16x32_f16(a, wB1[1][kk], acc1, 0,0,0);
      }
#pragma unroll
      for (int i = 0; i < 4; ++i) {
        Hh[4*g + i][32*w + m]      = (_Float16)fast_tanh(acc0[i]);
        Hh[4*g + i][32*w + 16 + m] = (_Float16)fast_tanh(acc1[i]);
      }
      __syncthreads();

      // layer 2: K = H @ W2 + b2
      f32x4 accA = { bb2, bb2, bb2, bb2 };
      f32x4 accB = { 0.f, 0.f, 0.f, 0.f };
#pragma unroll
      for (int kk = 0; kk < 4; ++kk) {
        f16x8 aA = ld_frag(&Hh[m][kk*32 + 8*g]);
        f16x8 aB = ld_frag(&Hh[m][(kk+4)*32 + 8*g]);
        accA = __builtin_amdgcn_mfma_f32_16x16x32_f16(aA, wB2[kk],   accA, 0,0,0);
        accB = __builtin_amdgcn_mfma_f32_16x16x32_f16(aB, wB2[kk+4], accB, 0,0,0);
      }

      // RK4 (3/8 rule) bookkeeping
      if (stage == 0) {
#pragma unroll
        for (int i = 0; i < 4; ++i) { k1[i] = accA[i]+accB[i]; yn[i] = y[i] + third*k1[i]; }
      } else if (stage == 1) {
#pragma unroll
        for (int i = 0; i < 4; ++i) { k2[i] = accA[i]+accB[i]; yn[i] = y[i] + dt*(k2[i] - k1[i]*(1.f/3.f)); }
      } else if (stage == 2) {
#pragma unroll
        for (int i = 0; i < 4; ++i) { k3[i] = accA[i]+accB[i]; yn[i] = y[i] + dt*(k1[i] - k2[i] + k3[i]); }
      } else {
#pragma unroll
        for (int i = 0; i < 4; ++i) {
          float k4 = accA[i]+accB[i];
          y[i] += dt*0.125f*(k1[i] + 3.f*(k2[i]+k3[i]) + k4);
          yn[i] = y[i];
        }
        if (col < 64) {
#pragma unroll
          for (int i = 0; i < 4; ++i)
            out[(step+1)*OUTSTRIDE + (row0 + 4*g + i)*64 + col] = y[i];
        }
      }
    }
  }
}

extern "C" void kernel_launch(void* const* d_in, const int* in_sizes, int n_in,
                              void* d_out, int out_size, void* d_ws, size_t ws_size,
                              hipStream_t stream) {
  const float* x0 = (const float*)d_in[0];
  const float* t  = (const float*)d_in[1];
  const float* W1 = (const float*)d_in[2];
  const float* b1 = (const float*)d_in[3];
  const float* W2 = (const float*)d_in[4];
  const float* b2 = (const float*)d_in[5];
  float* out = (float*)d_out;
  hipLaunchKernelGGL(node_rk4_kernel, dim3(4096/BM), dim3(512), 0, stream,
                     x0, t, W1, b1, W2, b2, out);
}